// Round 7
// baseline (249.631 us; speedup 1.0000x reference)
//
#include <hip/hip_runtime.h>

// 3D Spatial Transformer: trilinear grid_sample, align_corners=False,
// padding_mode='border'.  B=2, C=2, D=H=W=128, fp32.
// Latency-bound fix (R5 data): phase-split so ALL 64 gathers are in
// flight before any consumption.  Phase 1: indices+weights for 4 voxels.
// Phase 2: 64 gather loads into registers.  sched_barrier.  Phase 3: math.
// __launch_bounds__(256,2) lets the allocator keep the big load window
// (R5's 40-VGPR schedule had ~zero memory-level parallelism -> 161us).

#define Dv 128
#define Hv 128
#define Wv 128
#define Bv 2
#define Cv 2
#define Nv (Dv * Hv * Wv)   // 2097152 = 2^21
#define Qv (Nv / 4)         // 524288  = 2^19 float4-groups per volume

typedef float f32x4 __attribute__((ext_vector_type(4)));

__global__ __launch_bounds__(256, 2) void stn3d_kernel(
    const float* __restrict__ image,
    const float* __restrict__ flow,
    float* __restrict__ out)
{
    const unsigned gid = blockIdx.x * blockDim.x + threadIdx.x;  // over Bv*Qv = 2^20
    const int b = (int)(gid >> 19);
    const int q = (int)(gid & (Qv - 1));
    const int v4 = q << 2;                 // first voxel of this thread's group
    const int xb = v4 & (Wv - 1);          // x of voxel 0 (4 | 128 so row-aligned)
    const int y  = (v4 >> 7) & (Hv - 1);
    const int z  = v4 >> 14;

    // --- coalesced 16B/lane read-once flow loads (nontemporal) ---
    const float* fb = flow + (size_t)b * 3u * Nv;
    const f32x4 fx4 = __builtin_nontemporal_load((const f32x4*)(fb) + q);
    const f32x4 fy4 = __builtin_nontemporal_load((const f32x4*)(fb + Nv) + q);
    const f32x4 fz4 = __builtin_nontemporal_load((const f32x4*)(fb + 2 * Nv) + q);

    const float* ic0 = image + (size_t)b * Cv * Nv;  // channel 0 volume
    const float* ic1 = ic0 + Nv;                     // channel 1 volume

    const float step = 2.0f / 127.0f;
    const float gyb = -1.0f + step * (float)y;
    const float gzb = -1.0f + step * (float)z;

    // ---- Phase 1: all indices + weights (static after unroll) ----
    int   idx[4][8];
    float wgt[4][8];
#pragma unroll
    for (int i = 0; i < 4; ++i) {
        // reference math, fp32, same op order
        const float gx = (-1.0f + step * (float)(xb + i)) + 2.0f * fx4[i] / 127.0f;
        const float gy = gyb + 2.0f * fy4[i] / 127.0f;
        const float gz = gzb + 2.0f * fz4[i] / 127.0f;
        float ix = ((gx + 1.0f) * (float)Wv - 1.0f) * 0.5f;
        float iy = ((gy + 1.0f) * (float)Hv - 1.0f) * 0.5f;
        float iz = ((gz + 1.0f) * (float)Dv - 1.0f) * 0.5f;
        ix = fminf(fmaxf(ix, 0.0f), (float)(Wv - 1));
        iy = fminf(fmaxf(iy, 0.0f), (float)(Hv - 1));
        iz = fminf(fmaxf(iz, 0.0f), (float)(Dv - 1));

        const float x0f = floorf(ix), y0f = floorf(iy), z0f = floorf(iz);
        const float tx = ix - x0f, ty = iy - y0f, tz = iz - z0f;
        const int x0 = (int)x0f, y0 = (int)y0f, z0 = (int)z0f;
        const int x1 = min(x0 + 1, Wv - 1);
        const int y1 = min(y0 + 1, Hv - 1);
        const int z1 = min(z0 + 1, Dv - 1);

        const int zy00 = ((z0 << 7) + y0) << 7;
        const int zy01 = ((z0 << 7) + y1) << 7;
        const int zy10 = ((z1 << 7) + y0) << 7;
        const int zy11 = ((z1 << 7) + y1) << 7;
        idx[i][0] = zy00 + x0;  idx[i][1] = zy00 + x1;
        idx[i][2] = zy01 + x0;  idx[i][3] = zy01 + x1;
        idx[i][4] = zy10 + x0;  idx[i][5] = zy10 + x1;
        idx[i][6] = zy11 + x0;  idx[i][7] = zy11 + x1;

        const float sx = 1.0f - tx, sy = 1.0f - ty, sz = 1.0f - tz;
        wgt[i][0] = sz * sy * sx;  wgt[i][1] = sz * sy * tx;
        wgt[i][2] = sz * ty * sx;  wgt[i][3] = sz * ty * tx;
        wgt[i][4] = tz * sy * sx;  wgt[i][5] = tz * sy * tx;
        wgt[i][6] = tz * ty * sx;  wgt[i][7] = tz * ty * tx;
    }

    // ---- Phase 2: issue all 64 gathers (keep them co-resident) ----
    float c0[4][8], c1[4][8];
#pragma unroll
    for (int i = 0; i < 4; ++i) {
#pragma unroll
        for (int k = 0; k < 8; ++k) {
            c0[i][k] = ic0[idx[i][k]];
            c1[i][k] = ic1[idx[i][k]];
        }
    }

    // keep the math from being hoisted between the loads (which would let
    // the scheduler re-serialize the load stream to shrink registers)
    __builtin_amdgcn_sched_barrier(0);

    // ---- Phase 3: accumulate, reference corner order ----
    f32x4 s0, s1;
#pragma unroll
    for (int i = 0; i < 4; ++i) {
        float r0 = c0[i][0] * wgt[i][0];
        r0 += c0[i][1] * wgt[i][1];
        r0 += c0[i][2] * wgt[i][2];
        r0 += c0[i][3] * wgt[i][3];
        r0 += c0[i][4] * wgt[i][4];
        r0 += c0[i][5] * wgt[i][5];
        r0 += c0[i][6] * wgt[i][6];
        r0 += c0[i][7] * wgt[i][7];
        s0[i] = r0;
        float r1 = c1[i][0] * wgt[i][0];
        r1 += c1[i][1] * wgt[i][1];
        r1 += c1[i][2] * wgt[i][2];
        r1 += c1[i][3] * wgt[i][3];
        r1 += c1[i][4] * wgt[i][4];
        r1 += c1[i][5] * wgt[i][5];
        r1 += c1[i][6] * wgt[i][6];
        r1 += c1[i][7] * wgt[i][7];
        s1[i] = r1;
    }

    // ---- nontemporal 16B stores (write-once output) ----
    float* ob = out + (size_t)b * Cv * Nv;
    __builtin_nontemporal_store(s0, (f32x4*)(ob) + q);
    __builtin_nontemporal_store(s1, (f32x4*)(ob + Nv) + q);
}

extern "C" void kernel_launch(void* const* d_in, const int* in_sizes, int n_in,
                              void* d_out, int out_size, void* d_ws, size_t ws_size,
                              hipStream_t stream) {
    const float* image = (const float*)d_in[0];
    const float* flow  = (const float*)d_in[1];
    float* out = (float*)d_out;

    const int total = Bv * Qv;            // 1,048,576 threads
    const int block = 256;
    const int grid = total / block;       // 4096 blocks
    stn3d_kernel<<<grid, block, 0, stream>>>(image, flow, out);
}

// Round 8
// 184.429 us; speedup vs baseline: 1.3535x; 1.3535x over previous
//
#include <hip/hip_runtime.h>

// 3D Spatial Transformer: trilinear grid_sample, align_corners=False,
// padding_mode='border'.  B=2, C=2, D=H=W=128, fp32.
//
// R5/R7 evidence: occupancy-independent 161us with all pipes <10% busy ->
// bound by the per-CU vector-memory front-end processing divergent gather
// lanes/lines sequentially.  Only (gather instrs x lanes) matters.
// Fix: repack image to channel-interleaved [D][H][W][C=2] in d_ws, then one
// 16B gather per (z,y)-row fetches both channels x both x-corners:
// 64 scalar gathers/thread -> 16 float4 gathers/thread.

#define Dv 128
#define Hv 128
#define Wv 128
#define Bv 2
#define Cv 2
#define Nv (Dv * Hv * Wv)   // 2097152 = 2^21
#define Qv (Nv / 4)         // 524288  = 2^19 float4-groups per volume

typedef float f32x4 __attribute__((ext_vector_type(4)));
typedef f32x4 f32x4_a8 __attribute__((aligned(8)));  // 8B-aligned 16B load

// ---------------- repack: [C][D][H][W] -> [D][H][W][C] (float2/voxel) -----
__global__ __launch_bounds__(256) void repack_kernel(
    const float* __restrict__ img, float* __restrict__ ws)
{
    const unsigned gid = blockIdx.x * blockDim.x + threadIdx.x;  // Bv*Qv
    const int b = (int)(gid >> 19);
    const int q = (int)(gid & (Qv - 1));
    const float* c0 = img + (size_t)b * Cv * Nv;
    const float* c1 = c0 + Nv;
    const f32x4 a  = __builtin_nontemporal_load((const f32x4*)c0 + q);
    const f32x4 bb = __builtin_nontemporal_load((const f32x4*)c1 + q);
    f32x4 lo, hi;
    lo[0] = a[0]; lo[1] = bb[0]; lo[2] = a[1]; lo[3] = bb[1];
    hi[0] = a[2]; hi[1] = bb[2]; hi[2] = a[3]; hi[3] = bb[3];
    float* wb = ws + (size_t)b * 2u * Nv + (size_t)q * 8u;
    *(f32x4*)(wb)     = lo;     // 32B-aligned
    *(f32x4*)(wb + 4) = hi;
}

// ---------------- main: gather from interleaved ws ------------------------
__global__ __launch_bounds__(256, 2) void stn3d_kernel(
    const float* __restrict__ ws,
    const float* __restrict__ flow,
    float* __restrict__ out)
{
    const unsigned gid = blockIdx.x * blockDim.x + threadIdx.x;  // Bv*Qv
    const int b = (int)(gid >> 19);
    const int q = (int)(gid & (Qv - 1));
    const int v4 = q << 2;
    const int xb = v4 & (Wv - 1);
    const int y  = (v4 >> 7) & (Hv - 1);
    const int z  = v4 >> 14;

    const float* fb = flow + (size_t)b * 3u * Nv;
    const f32x4 fx4 = __builtin_nontemporal_load((const f32x4*)(fb) + q);
    const f32x4 fy4 = __builtin_nontemporal_load((const f32x4*)(fb + Nv) + q);
    const f32x4 fz4 = __builtin_nontemporal_load((const f32x4*)(fb + 2 * Nv) + q);

    const float* wsb = ws + (size_t)b * 2u * Nv;  // float2 per voxel

    const float step = 2.0f / 127.0f;
    const float gyb = -1.0f + step * (float)y;
    const float gzb = -1.0f + step * (float)z;

    // ---- Phase 1: indices + fractional weights ----
    int   row[4][4];      // float2-index of (zXyY, xbase) per voxel, 4 rows
    int   xs[4];          // 1 iff x0==127 (select upper pair for x0)
    float tw[4][3];       // tx, ty, tz
#pragma unroll
    for (int i = 0; i < 4; ++i) {
        const float gx = (-1.0f + step * (float)(xb + i)) + 2.0f * fx4[i] / 127.0f;
        const float gy = gyb + 2.0f * fy4[i] / 127.0f;
        const float gz = gzb + 2.0f * fz4[i] / 127.0f;
        float ix = ((gx + 1.0f) * (float)Wv - 1.0f) * 0.5f;
        float iy = ((gy + 1.0f) * (float)Hv - 1.0f) * 0.5f;
        float iz = ((gz + 1.0f) * (float)Dv - 1.0f) * 0.5f;
        ix = fminf(fmaxf(ix, 0.0f), (float)(Wv - 1));
        iy = fminf(fmaxf(iy, 0.0f), (float)(Hv - 1));
        iz = fminf(fmaxf(iz, 0.0f), (float)(Dv - 1));

        const float x0f = floorf(ix), y0f = floorf(iy), z0f = floorf(iz);
        tw[i][0] = ix - x0f; tw[i][1] = iy - y0f; tw[i][2] = iz - z0f;
        const int x0 = (int)x0f, y0 = (int)y0f, z0 = (int)z0f;
        const int y1 = min(y0 + 1, Hv - 1);
        const int z1 = min(z0 + 1, Dv - 1);
        const int xbase = min(x0, Wv - 2);      // load covers xbase, xbase+1
        xs[i] = x0 - xbase;                     // 0 normally, 1 iff x0==127

        row[i][0] = ((((z0 << 7) + y0) << 7) + xbase);
        row[i][1] = ((((z0 << 7) + y1) << 7) + xbase);
        row[i][2] = ((((z1 << 7) + y0) << 7) + xbase);
        row[i][3] = ((((z1 << 7) + y1) << 7) + xbase);
    }

    // ---- Phase 2: 16 gathers of 16B: [c0(xb), c1(xb), c0(xb+1), c1(xb+1)] ----
    f32x4 g[4][4];
#pragma unroll
    for (int i = 0; i < 4; ++i) {
#pragma unroll
        for (int r = 0; r < 4; ++r) {
            g[i][r] = *(const f32x4_a8*)(wsb + 2u * (unsigned)row[i][r]);
        }
    }

    __builtin_amdgcn_sched_barrier(0);

    // ---- Phase 3: weights + accumulate (reference corner order) ----
    f32x4 s0, s1;
#pragma unroll
    for (int i = 0; i < 4; ++i) {
        const float tx = tw[i][0], ty = tw[i][1], tz = tw[i][2];
        const float sx = 1.0f - tx, sy = 1.0f - ty, sz = 1.0f - tz;
        const float w000 = sz * sy * sx, w001 = sz * sy * tx;
        const float w010 = sz * ty * sx, w011 = sz * ty * tx;
        const float w100 = tz * sy * sx, w101 = tz * sy * tx;
        const float w110 = tz * ty * sx, w111 = tz * ty * tx;
        const bool hi = (xs[i] != 0);

        // x0 values: elements (0,1) normally, (2,3) when x0==127.
        const float a00 = hi ? g[i][0][2] : g[i][0][0];  // c0 @ (z0,y0,x0)
        const float b00 = hi ? g[i][0][3] : g[i][0][1];  // c1
        const float a01 = hi ? g[i][1][2] : g[i][1][0];  // (z0,y1,x0)
        const float b01 = hi ? g[i][1][3] : g[i][1][1];
        const float a10 = hi ? g[i][2][2] : g[i][2][0];  // (z1,y0,x0)
        const float b10 = hi ? g[i][2][3] : g[i][2][1];
        const float a11 = hi ? g[i][3][2] : g[i][3][0];  // (z1,y1,x0)
        const float b11 = hi ? g[i][3][3] : g[i][3][1];

        float r0 = a00 * w000;
        r0 += g[i][0][2] * w001;      // x1 always at elements (2,3)
        r0 += a01 * w010;
        r0 += g[i][1][2] * w011;
        r0 += a10 * w100;
        r0 += g[i][2][2] * w101;
        r0 += a11 * w110;
        r0 += g[i][3][2] * w111;
        s0[i] = r0;

        float r1 = b00 * w000;
        r1 += g[i][0][3] * w001;
        r1 += b01 * w010;
        r1 += g[i][1][3] * w011;
        r1 += b10 * w100;
        r1 += g[i][2][3] * w101;
        r1 += b11 * w110;
        r1 += g[i][3][3] * w111;
        s1[i] = r1;
    }

    float* ob = out + (size_t)b * Cv * Nv;
    __builtin_nontemporal_store(s0, (f32x4*)(ob) + q);
    __builtin_nontemporal_store(s1, (f32x4*)(ob + Nv) + q);
}

// ---------------- fallback (ws too small): R7 planar path -----------------
__global__ __launch_bounds__(256, 2) void stn3d_planar_kernel(
    const float* __restrict__ image,
    const float* __restrict__ flow,
    float* __restrict__ out)
{
    const unsigned gid = blockIdx.x * blockDim.x + threadIdx.x;
    const int b = (int)(gid >> 19);
    const int q = (int)(gid & (Qv - 1));
    const int v4 = q << 2;
    const int xb = v4 & (Wv - 1);
    const int y  = (v4 >> 7) & (Hv - 1);
    const int z  = v4 >> 14;

    const float* fb = flow + (size_t)b * 3u * Nv;
    const f32x4 fx4 = __builtin_nontemporal_load((const f32x4*)(fb) + q);
    const f32x4 fy4 = __builtin_nontemporal_load((const f32x4*)(fb + Nv) + q);
    const f32x4 fz4 = __builtin_nontemporal_load((const f32x4*)(fb + 2 * Nv) + q);

    const float* ic0 = image + (size_t)b * Cv * Nv;
    const float* ic1 = ic0 + Nv;
    const float step = 2.0f / 127.0f;
    const float gyb = -1.0f + step * (float)y;
    const float gzb = -1.0f + step * (float)z;

    f32x4 s0, s1;
#pragma unroll
    for (int i = 0; i < 4; ++i) {
        const float gx = (-1.0f + step * (float)(xb + i)) + 2.0f * fx4[i] / 127.0f;
        const float gy = gyb + 2.0f * fy4[i] / 127.0f;
        const float gz = gzb + 2.0f * fz4[i] / 127.0f;
        float ix = ((gx + 1.0f) * (float)Wv - 1.0f) * 0.5f;
        float iy = ((gy + 1.0f) * (float)Hv - 1.0f) * 0.5f;
        float iz = ((gz + 1.0f) * (float)Dv - 1.0f) * 0.5f;
        ix = fminf(fmaxf(ix, 0.0f), (float)(Wv - 1));
        iy = fminf(fmaxf(iy, 0.0f), (float)(Hv - 1));
        iz = fminf(fmaxf(iz, 0.0f), (float)(Dv - 1));
        const float x0f = floorf(ix), y0f = floorf(iy), z0f = floorf(iz);
        const float tx = ix - x0f, ty = iy - y0f, tz = iz - z0f;
        const int x0 = (int)x0f, y0 = (int)y0f, z0 = (int)z0f;
        const int x1 = min(x0 + 1, Wv - 1);
        const int y1 = min(y0 + 1, Hv - 1);
        const int z1 = min(z0 + 1, Dv - 1);
        const int zy00 = ((z0 << 7) + y0) << 7;
        const int zy01 = ((z0 << 7) + y1) << 7;
        const int zy10 = ((z1 << 7) + y0) << 7;
        const int zy11 = ((z1 << 7) + y1) << 7;
        const float sx = 1.0f - tx, sy = 1.0f - ty, sz = 1.0f - tz;
        const float w000 = sz*sy*sx, w001 = sz*sy*tx, w010 = sz*ty*sx, w011 = sz*ty*tx;
        const float w100 = tz*sy*sx, w101 = tz*sy*tx, w110 = tz*ty*sx, w111 = tz*ty*tx;
        float r0 = ic0[zy00+x0]*w000 + ic0[zy00+x1]*w001 + ic0[zy01+x0]*w010 + ic0[zy01+x1]*w011
                 + ic0[zy10+x0]*w100 + ic0[zy10+x1]*w101 + ic0[zy11+x0]*w110 + ic0[zy11+x1]*w111;
        float r1 = ic1[zy00+x0]*w000 + ic1[zy00+x1]*w001 + ic1[zy01+x0]*w010 + ic1[zy01+x1]*w011
                 + ic1[zy10+x0]*w100 + ic1[zy10+x1]*w101 + ic1[zy11+x0]*w110 + ic1[zy11+x1]*w111;
        s0[i] = r0; s1[i] = r1;
    }
    float* ob = out + (size_t)b * Cv * Nv;
    __builtin_nontemporal_store(s0, (f32x4*)(ob) + q);
    __builtin_nontemporal_store(s1, (f32x4*)(ob + Nv) + q);
}

extern "C" void kernel_launch(void* const* d_in, const int* in_sizes, int n_in,
                              void* d_out, int out_size, void* d_ws, size_t ws_size,
                              hipStream_t stream) {
    const float* image = (const float*)d_in[0];
    const float* flow  = (const float*)d_in[1];
    float* out = (float*)d_out;

    const int total = Bv * Qv;            // 1,048,576 threads
    const int block = 256;
    const int grid = total / block;       // 4096 blocks

    const size_t ws_needed = (size_t)Bv * Nv * Cv * sizeof(float);  // 33.6 MB
    if (ws_size >= ws_needed) {
        float* ws = (float*)d_ws;
        repack_kernel<<<grid, block, 0, stream>>>(image, ws);
        stn3d_kernel<<<grid, block, 0, stream>>>(ws, flow, out);
    } else {
        stn3d_planar_kernel<<<grid, block, 0, stream>>>(image, flow, out);
    }
}

// Round 9
// 182.366 us; speedup vs baseline: 1.3688x; 1.0113x over previous
//
#include <hip/hip_runtime.h>

// 3D Spatial Transformer: trilinear grid_sample, align_corners=False,
// padding_mode='border'.  B=2, C=2, D=H=W=128, fp32.
//
// R8 evidence: interleaved-gather kernel at 76us with all pipes <20% ->
// bound by random 64B line-fill traffic to L3/fabric (~13 TB/s observed).
// This round: XCD-chunked block swizzle (bijective, 4096%8==0) on BOTH
// repack and main so each XCD's 4MB L2 holds its own z-slab of the
// interleaved volume; repack warms the slab, main's gathers hit L2.

#define Dv 128
#define Hv 128
#define Wv 128
#define Bv 2
#define Cv 2
#define Nv (Dv * Hv * Wv)   // 2097152 = 2^21
#define Qv (Nv / 4)         // 524288  = 2^19 float4-groups per volume
#define NBLK 4096
#define NXCD 8
#define BPX (NBLK / NXCD)   // 512 blocks per XCD

typedef float f32x4 __attribute__((ext_vector_type(4)));
typedef f32x4 f32x4_a8 __attribute__((aligned(8)));  // 8B-aligned 16B load

// physical blockIdx -> logical block id; XCD k (phys bid%8) gets the
// contiguous logical range [k*512,(k+1)*512) = a contiguous (b,z)-slab.
__device__ __forceinline__ unsigned xcd_remap(unsigned bid) {
    return (bid & (NXCD - 1)) * BPX + (bid >> 3);
}

// ---------------- repack: [C][D][H][W] -> [D][H][W][C] (float2/voxel) -----
__global__ __launch_bounds__(256) void repack_kernel(
    const float* __restrict__ img, float* __restrict__ ws)
{
    const unsigned gid = xcd_remap(blockIdx.x) * blockDim.x + threadIdx.x;  // Bv*Qv
    const int b = (int)(gid >> 19);
    const int q = (int)(gid & (Qv - 1));
    const float* c0 = img + (size_t)b * Cv * Nv;
    const float* c1 = c0 + Nv;
    const f32x4 a  = __builtin_nontemporal_load((const f32x4*)c0 + q);
    const f32x4 bb = __builtin_nontemporal_load((const f32x4*)c1 + q);
    f32x4 lo, hi;
    lo[0] = a[0]; lo[1] = bb[0]; lo[2] = a[1]; lo[3] = bb[1];
    hi[0] = a[2]; hi[1] = bb[2]; hi[2] = a[3]; hi[3] = bb[3];
    float* wb = ws + (size_t)b * 2u * Nv + (size_t)q * 8u;
    *(f32x4*)(wb)     = lo;     // regular stores: keep slab resident in L2
    *(f32x4*)(wb + 4) = hi;
}

// ---------------- main: gather from interleaved ws ------------------------
__global__ __launch_bounds__(256, 2) void stn3d_kernel(
    const float* __restrict__ ws,
    const float* __restrict__ flow,
    float* __restrict__ out)
{
    const unsigned gid = xcd_remap(blockIdx.x) * blockDim.x + threadIdx.x;  // Bv*Qv
    const int b = (int)(gid >> 19);
    const int q = (int)(gid & (Qv - 1));
    const int v4 = q << 2;
    const int xb = v4 & (Wv - 1);
    const int y  = (v4 >> 7) & (Hv - 1);
    const int z  = v4 >> 14;

    const float* fb = flow + (size_t)b * 3u * Nv;
    const f32x4 fx4 = __builtin_nontemporal_load((const f32x4*)(fb) + q);
    const f32x4 fy4 = __builtin_nontemporal_load((const f32x4*)(fb + Nv) + q);
    const f32x4 fz4 = __builtin_nontemporal_load((const f32x4*)(fb + 2 * Nv) + q);

    const float* wsb = ws + (size_t)b * 2u * Nv;  // float2 per voxel

    const float step = 2.0f / 127.0f;
    const float gyb = -1.0f + step * (float)y;
    const float gzb = -1.0f + step * (float)z;

    // ---- Phase 1: indices + fractional weights ----
    int   row[4][4];
    int   xs[4];          // 1 iff x0==127 (select upper pair for x0)
    float tw[4][3];       // tx, ty, tz
#pragma unroll
    for (int i = 0; i < 4; ++i) {
        const float gx = (-1.0f + step * (float)(xb + i)) + 2.0f * fx4[i] / 127.0f;
        const float gy = gyb + 2.0f * fy4[i] / 127.0f;
        const float gz = gzb + 2.0f * fz4[i] / 127.0f;
        float ix = ((gx + 1.0f) * (float)Wv - 1.0f) * 0.5f;
        float iy = ((gy + 1.0f) * (float)Hv - 1.0f) * 0.5f;
        float iz = ((gz + 1.0f) * (float)Dv - 1.0f) * 0.5f;
        ix = fminf(fmaxf(ix, 0.0f), (float)(Wv - 1));
        iy = fminf(fmaxf(iy, 0.0f), (float)(Hv - 1));
        iz = fminf(fmaxf(iz, 0.0f), (float)(Dv - 1));

        const float x0f = floorf(ix), y0f = floorf(iy), z0f = floorf(iz);
        tw[i][0] = ix - x0f; tw[i][1] = iy - y0f; tw[i][2] = iz - z0f;
        const int x0 = (int)x0f, y0 = (int)y0f, z0 = (int)z0f;
        const int y1 = min(y0 + 1, Hv - 1);
        const int z1 = min(z0 + 1, Dv - 1);
        const int xbase = min(x0, Wv - 2);      // load covers xbase, xbase+1
        xs[i] = x0 - xbase;                     // 0 normally, 1 iff x0==127

        row[i][0] = ((((z0 << 7) + y0) << 7) + xbase);
        row[i][1] = ((((z0 << 7) + y1) << 7) + xbase);
        row[i][2] = ((((z1 << 7) + y0) << 7) + xbase);
        row[i][3] = ((((z1 << 7) + y1) << 7) + xbase);
    }

    // ---- Phase 2: 16 gathers of 16B: [c0(xb), c1(xb), c0(xb+1), c1(xb+1)] ----
    f32x4 g[4][4];
#pragma unroll
    for (int i = 0; i < 4; ++i) {
#pragma unroll
        for (int r = 0; r < 4; ++r) {
            g[i][r] = *(const f32x4_a8*)(wsb + 2u * (unsigned)row[i][r]);
        }
    }

    __builtin_amdgcn_sched_barrier(0);

    // ---- Phase 3: weights + accumulate (reference corner order) ----
    f32x4 s0, s1;
#pragma unroll
    for (int i = 0; i < 4; ++i) {
        const float tx = tw[i][0], ty = tw[i][1], tz = tw[i][2];
        const float sx = 1.0f - tx, sy = 1.0f - ty, sz = 1.0f - tz;
        const float w000 = sz * sy * sx, w001 = sz * sy * tx;
        const float w010 = sz * ty * sx, w011 = sz * ty * tx;
        const float w100 = tz * sy * sx, w101 = tz * sy * tx;
        const float w110 = tz * ty * sx, w111 = tz * ty * tx;
        const bool hi = (xs[i] != 0);

        const float a00 = hi ? g[i][0][2] : g[i][0][0];
        const float b00 = hi ? g[i][0][3] : g[i][0][1];
        const float a01 = hi ? g[i][1][2] : g[i][1][0];
        const float b01 = hi ? g[i][1][3] : g[i][1][1];
        const float a10 = hi ? g[i][2][2] : g[i][2][0];
        const float b10 = hi ? g[i][2][3] : g[i][2][1];
        const float a11 = hi ? g[i][3][2] : g[i][3][0];
        const float b11 = hi ? g[i][3][3] : g[i][3][1];

        float r0 = a00 * w000;
        r0 += g[i][0][2] * w001;
        r0 += a01 * w010;
        r0 += g[i][1][2] * w011;
        r0 += a10 * w100;
        r0 += g[i][2][2] * w101;
        r0 += a11 * w110;
        r0 += g[i][3][2] * w111;
        s0[i] = r0;

        float r1 = b00 * w000;
        r1 += g[i][0][3] * w001;
        r1 += b01 * w010;
        r1 += g[i][1][3] * w011;
        r1 += b10 * w100;
        r1 += g[i][2][3] * w101;
        r1 += b11 * w110;
        r1 += g[i][3][3] * w111;
        s1[i] = r1;
    }

    float* ob = out + (size_t)b * Cv * Nv;
    __builtin_nontemporal_store(s0, (f32x4*)(ob) + q);
    __builtin_nontemporal_store(s1, (f32x4*)(ob + Nv) + q);
}

// ---------------- fallback (ws too small): R7 planar path -----------------
__global__ __launch_bounds__(256, 2) void stn3d_planar_kernel(
    const float* __restrict__ image,
    const float* __restrict__ flow,
    float* __restrict__ out)
{
    const unsigned gid = blockIdx.x * blockDim.x + threadIdx.x;
    const int b = (int)(gid >> 19);
    const int q = (int)(gid & (Qv - 1));
    const int v4 = q << 2;
    const int xb = v4 & (Wv - 1);
    const int y  = (v4 >> 7) & (Hv - 1);
    const int z  = v4 >> 14;

    const float* fb = flow + (size_t)b * 3u * Nv;
    const f32x4 fx4 = __builtin_nontemporal_load((const f32x4*)(fb) + q);
    const f32x4 fy4 = __builtin_nontemporal_load((const f32x4*)(fb + Nv) + q);
    const f32x4 fz4 = __builtin_nontemporal_load((const f32x4*)(fb + 2 * Nv) + q);

    const float* ic0 = image + (size_t)b * Cv * Nv;
    const float* ic1 = ic0 + Nv;
    const float step = 2.0f / 127.0f;
    const float gyb = -1.0f + step * (float)y;
    const float gzb = -1.0f + step * (float)z;

    f32x4 s0, s1;
#pragma unroll
    for (int i = 0; i < 4; ++i) {
        const float gx = (-1.0f + step * (float)(xb + i)) + 2.0f * fx4[i] / 127.0f;
        const float gy = gyb + 2.0f * fy4[i] / 127.0f;
        const float gz = gzb + 2.0f * fz4[i] / 127.0f;
        float ix = ((gx + 1.0f) * (float)Wv - 1.0f) * 0.5f;
        float iy = ((gy + 1.0f) * (float)Hv - 1.0f) * 0.5f;
        float iz = ((gz + 1.0f) * (float)Dv - 1.0f) * 0.5f;
        ix = fminf(fmaxf(ix, 0.0f), (float)(Wv - 1));
        iy = fminf(fmaxf(iy, 0.0f), (float)(Hv - 1));
        iz = fminf(fmaxf(iz, 0.0f), (float)(Dv - 1));
        const float x0f = floorf(ix), y0f = floorf(iy), z0f = floorf(iz);
        const float tx = ix - x0f, ty = iy - y0f, tz = iz - z0f;
        const int x0 = (int)x0f, y0 = (int)y0f, z0 = (int)z0f;
        const int x1 = min(x0 + 1, Wv - 1);
        const int y1 = min(y0 + 1, Hv - 1);
        const int z1 = min(z0 + 1, Dv - 1);
        const int zy00 = ((z0 << 7) + y0) << 7;
        const int zy01 = ((z0 << 7) + y1) << 7;
        const int zy10 = ((z1 << 7) + y0) << 7;
        const int zy11 = ((z1 << 7) + y1) << 7;
        const float sx = 1.0f - tx, sy = 1.0f - ty, sz = 1.0f - tz;
        const float w000 = sz*sy*sx, w001 = sz*sy*tx, w010 = sz*ty*sx, w011 = sz*ty*tx;
        const float w100 = tz*sy*sx, w101 = tz*sy*tx, w110 = tz*ty*sx, w111 = tz*ty*tx;
        float r0 = ic0[zy00+x0]*w000 + ic0[zy00+x1]*w001 + ic0[zy01+x0]*w010 + ic0[zy01+x1]*w011
                 + ic0[zy10+x0]*w100 + ic0[zy10+x1]*w101 + ic0[zy11+x0]*w110 + ic0[zy11+x1]*w111;
        float r1 = ic1[zy00+x0]*w000 + ic1[zy00+x1]*w001 + ic1[zy01+x0]*w010 + ic1[zy01+x1]*w011
                 + ic1[zy10+x0]*w100 + ic1[zy10+x1]*w101 + ic1[zy11+x0]*w110 + ic1[zy11+x1]*w111;
        s0[i] = r0; s1[i] = r1;
    }
    float* ob = out + (size_t)b * Cv * Nv;
    __builtin_nontemporal_store(s0, (f32x4*)(ob) + q);
    __builtin_nontemporal_store(s1, (f32x4*)(ob + Nv) + q);
}

extern "C" void kernel_launch(void* const* d_in, const int* in_sizes, int n_in,
                              void* d_out, int out_size, void* d_ws, size_t ws_size,
                              hipStream_t stream) {
    const float* image = (const float*)d_in[0];
    const float* flow  = (const float*)d_in[1];
    float* out = (float*)d_out;

    const int block = 256;

    const size_t ws_needed = (size_t)Bv * Nv * Cv * sizeof(float);  // 33.6 MB
    if (ws_size >= ws_needed) {
        float* ws = (float*)d_ws;
        repack_kernel<<<NBLK, block, 0, stream>>>(image, ws);
        stn3d_kernel<<<NBLK, block, 0, stream>>>(ws, flow, out);
    } else {
        stn3d_planar_kernel<<<NBLK, block, 0, stream>>>(image, flow, out);
    }
}